// Round 1
// baseline (203196.045 us; speedup 1.0000x reference)
//
#include <hip/hip_runtime.h>
#include <stdint.h>
#include <stddef.h>

#define TT 32768
#define HH 256

// ---------- bf16 helpers (manual, RNE) ----------
__device__ __forceinline__ float bf2f(unsigned short u) {
    unsigned int x = ((unsigned int)u) << 16;
    float f;
    __builtin_memcpy(&f, &x, 4);
    return f;
}
__device__ __forceinline__ unsigned short f2bf(float f) {
    unsigned int x;
    __builtin_memcpy(&x, &f, 4);
    unsigned int r = x + 0x7fffu + ((x >> 16) & 1u);
    return (unsigned short)(r >> 16);
}

// ---------- init: decay table + exchange-ring reset (runs every launch) ----------
__global__ void init_kernel(const int* __restrict__ ca,
                            float* __restrict__ decay,
                            unsigned long long* __restrict__ ring) {
    int i = blockIdx.x * 256 + threadIdx.x;
    if (i < TT) {
        float d = (i == 0) ? 0.f : (float)(ca[i] - ca[i - 1]);
        decay[i] = 1.f / logf(2.71828182845904523f + d);
    }
    if (i < 512) ring[i] = 0ull;   // tag 0 = invalid
}

// ---------- input-side projections: xproj[t][g*256+col] = inputs@W_g + b_g ----------
// g: 0=i, 1=f, 2=o, 3=c. C = A[32768x256] * W[256x256] per gate, tiled 64x64, BK=32.
template <bool XF32>
__global__ __launch_bounds__(256) void proj_kernel(
    const float* __restrict__ A,
    const float* __restrict__ W0, const float* __restrict__ W1,
    const float* __restrict__ W2, const float* __restrict__ W3,
    const float* __restrict__ B0, const float* __restrict__ B1,
    const float* __restrict__ B2, const float* __restrict__ B3,
    void* __restrict__ xproj) {
    __shared__ float As[32][65];
    __shared__ float Bs[32][65];
    const int tid = threadIdx.x;
    const int bm = blockIdx.x;   // 0..511 (t tiles)
    const int by = blockIdx.y;   // 0..15  (gate-col tiles)
    const int g = by >> 2;
    const int col0 = (by & 3) << 6;
    const float* W = (g == 0) ? W0 : (g == 1) ? W1 : (g == 2) ? W2 : W3;
    const float* Bv = (g == 0) ? B0 : (g == 1) ? B1 : (g == 2) ? B2 : B3;
    const int t0 = bm << 6;

    float acc[4][4] = {};
    const int tm = (tid & 15) << 2;
    const int tn = (tid >> 4) << 2;
    const int lrow = tid >> 2;         // A row 0..63
    const int lk = (tid & 3) << 3;     // A k  0,8,16,24
    const int brow = tid & 63;         // B n  0..63
    const int bk = (tid >> 6) << 3;    // B k  0,8,16,24

    for (int k0 = 0; k0 < 256; k0 += 32) {
        const float* asrc = A + (size_t)(t0 + lrow) * 256 + k0 + lk;
        float4 a0 = *(const float4*)asrc;
        float4 a1 = *(const float4*)(asrc + 4);
        As[lk + 0][lrow] = a0.x; As[lk + 1][lrow] = a0.y;
        As[lk + 2][lrow] = a0.z; As[lk + 3][lrow] = a0.w;
        As[lk + 4][lrow] = a1.x; As[lk + 5][lrow] = a1.y;
        As[lk + 6][lrow] = a1.z; As[lk + 7][lrow] = a1.w;
#pragma unroll
        for (int j = 0; j < 8; j++)
            Bs[bk + j][brow] = W[(size_t)(k0 + bk + j) * 256 + col0 + brow];
        __syncthreads();
#pragma unroll
        for (int kk = 0; kk < 32; ++kk) {
            float av[4], bv[4];
#pragma unroll
            for (int i = 0; i < 4; i++) av[i] = As[kk][tm + i];
#pragma unroll
            for (int j = 0; j < 4; j++) bv[j] = Bs[kk][tn + j];
#pragma unroll
            for (int i = 0; i < 4; i++)
#pragma unroll
                for (int j = 0; j < 4; j++)
                    acc[i][j] = fmaf(av[i], bv[j], acc[i][j]);
        }
        __syncthreads();
    }
#pragma unroll
    for (int i = 0; i < 4; i++) {
        const size_t rowoff = (size_t)(t0 + tm + i) * 1024 + ((size_t)g << 8) + col0;
#pragma unroll
        for (int j = 0; j < 4; j++) {
            float v = acc[i][j] + Bv[col0 + tn + j];
            if (XF32) ((float*)xproj)[rowoff + tn + j] = v;
            else      ((unsigned short*)xproj)[rowoff + tn + j] = f2bf(v);
        }
    }
}

// ---------- sequential scan: 16 persistent blocks, register-resident weights ----------
// Block b owns output cols [16b, 16b+16). Thread (cl = tid>>4, ks = tid&15):
//   col = 16b+cl, k-slice = [16ks, 16ks+16). Weights w[5][16] in VGPRs.
// Exchange: ring[2][256] of u64 words: low32 = (tag<<16)|h_bf16, high32 = (tag<<16)|c_bf16.
// tag = t+1 after step t. Depth-2 ring is race-free (overwrite of slot p-2 is gated,
// transitively, on every block having consumed p-2). No fences needed: per-word
// 8-byte agent-scope relaxed atomics carry data+tag together through the L3.
template <bool XF32>
__global__ __launch_bounds__(256, 1) void scan_kernel(
    const float* __restrict__ Wd, const float* __restrict__ bd,
    const float* __restrict__ Ui, const float* __restrict__ Uf,
    const float* __restrict__ Uo, const float* __restrict__ Uc,
    const void* __restrict__ xproj, const float* __restrict__ decay,
    unsigned long long* __restrict__ ring,
    float* __restrict__ out) {
    const int b = blockIdx.x, tid = threadIdx.x;
    const int cl = tid >> 4, ks = tid & 15;
    const int col = (b << 4) + cl;

    float w[5][16];
    {
        const float* mats[5] = {Wd, Ui, Uf, Uo, Uc};
#pragma unroll
        for (int m = 0; m < 5; m++)
#pragma unroll
            for (int j = 0; j < 16; j++)
                w[m][j] = mats[m][(size_t)((ks << 4) + j) * 256 + col];
    }
    const float bdv = bd[col];
    const bool owner = (ks == 0);
    float c_own = 0.f;

    for (int t = 0; t < TT; ++t) {
        // issue independent loads first so they fly during the poll
        float xi = 0.f, xf = 0.f, xo = 0.f, xc = 0.f, dt_ = 0.f;
        if (owner) {
            dt_ = decay[t];
            if (XF32) {
                const float* xp = (const float*)xproj + (size_t)t * 1024;
                xi = xp[col]; xf = xp[col + 256]; xo = xp[col + 512]; xc = xp[col + 768];
            } else {
                const unsigned short* xp = (const unsigned short*)xproj + (size_t)t * 1024;
                xi = bf2f(xp[col]); xf = bf2f(xp[col + 256]);
                xo = bf2f(xp[col + 512]); xc = bf2f(xp[col + 768]);
            }
        }

        float hs[16], cs[16];
        if (t == 0) {
#pragma unroll
            for (int j = 0; j < 16; j++) { hs[j] = 0.f; cs[j] = 0.f; }
        } else {
            unsigned long long* src = ring + (size_t)((t - 1) & 1) * 256 + (ks << 4);
            const unsigned int want = (unsigned int)t;  // tag of state after step t-1
            unsigned long long v[16];
#pragma unroll
            for (int j = 0; j < 16; j++)
                v[j] = __hip_atomic_load(src + j, __ATOMIC_RELAXED, __HIP_MEMORY_SCOPE_AGENT);
            for (;;) {
                bool ok = true;
#pragma unroll
                for (int j = 0; j < 16; j++) {
                    if ((((unsigned int)v[j]) >> 16) != want) {
                        v[j] = __hip_atomic_load(src + j, __ATOMIC_RELAXED, __HIP_MEMORY_SCOPE_AGENT);
                        if ((((unsigned int)v[j]) >> 16) != want) ok = false;
                    }
                }
                if (ok) break;
            }
#pragma unroll
            for (int j = 0; j < 16; j++) {
                hs[j] = bf2f((unsigned short)(v[j] & 0xffffu));
                cs[j] = bf2f((unsigned short)((v[j] >> 32) & 0xffffu));
            }
        }

        float a0 = 0.f, a1 = 0.f, a2 = 0.f, a3 = 0.f, a4 = 0.f;
#pragma unroll
        for (int j = 0; j < 16; j++) {
            a0 = fmaf(cs[j], w[0][j], a0);
            a1 = fmaf(hs[j], w[1][j], a1);
            a2 = fmaf(hs[j], w[2][j], a2);
            a3 = fmaf(hs[j], w[3][j], a3);
            a4 = fmaf(hs[j], w[4][j], a4);
        }
        // butterfly reduce over the 16-lane k-slice group (lane bits 0..3)
#pragma unroll
        for (int m = 1; m <= 8; m <<= 1) {
            a0 += __shfl_xor(a0, m);
            a1 += __shfl_xor(a1, m);
            a2 += __shfl_xor(a2, m);
            a3 += __shfl_xor(a3, m);
            a4 += __shfl_xor(a4, m);
        }

        if (owner) {
            float s = tanhf(a0 + bdv);
            float adj = (c_own - s) + s * dt_;
            float iv = 1.f / (1.f + __expf(-(a1 + xi)));
            float fv = 1.f / (1.f + __expf(-(a2 + xf)));
            float ov = 1.f / (1.f + __expf(-(a3 + xo)));
            float gv = tanhf(a4 + xc);
            float cn = fv * adj + iv * gv;
            float hn = ov * tanhf(c_own);          // uses PREV memory, per reference
            out[(size_t)t * 256 + col] = hn;
            unsigned int tag = (unsigned int)(t + 1);
            unsigned int w0 = (tag << 16) | (unsigned int)f2bf(hn);
            unsigned int w1 = (tag << 16) | (unsigned int)f2bf(cn);
            unsigned long long pv = (((unsigned long long)w1) << 32) | (unsigned long long)w0;
            __hip_atomic_store(ring + (size_t)(t & 1) * 256 + col, pv,
                               __ATOMIC_RELAXED, __HIP_MEMORY_SCOPE_AGENT);
            c_own = cn;
        }
    }
}

extern "C" void kernel_launch(void* const* d_in, const int* in_sizes, int n_in,
                              void* d_out, int out_size, void* d_ws, size_t ws_size,
                              hipStream_t stream) {
    const float* inputs = (const float*)d_in[0];
    const int* created = (const int*)d_in[1];
    const float* Wd = (const float*)d_in[2];
    // d_in[3] = U_d : unused by the reference
    const float* bd = (const float*)d_in[4];
    const float* Wf = (const float*)d_in[5];
    const float* Uf = (const float*)d_in[6];
    const float* bfp = (const float*)d_in[7];
    const float* Wi = (const float*)d_in[8];
    const float* Ui = (const float*)d_in[9];
    const float* bip = (const float*)d_in[10];
    const float* Wo = (const float*)d_in[11];
    const float* Uo = (const float*)d_in[12];
    const float* bop = (const float*)d_in[13];
    const float* Wc = (const float*)d_in[14];
    const float* Uc = (const float*)d_in[15];
    const float* bcp = (const float*)d_in[16];
    float* out = (float*)d_out;

    char* ws = (char*)d_ws;
    const size_t off_decay = 0;                    // 32768 * 4      = 131072
    const size_t off_ring  = 131072;               // 2*256*8        = 4096
    const size_t off_xproj = 135168;               // 33 * 4096, aligned
    const size_t need_f32 = off_xproj + (size_t)TT * 1024 * 4;  // ~128.1 MiB

    float* decay = (float*)(ws + off_decay);
    unsigned long long* ring = (unsigned long long*)(ws + off_ring);
    void* xproj = (void*)(ws + off_xproj);
    const bool xf32 = (ws_size >= need_f32);

    init_kernel<<<128, 256, 0, stream>>>(created, decay, ring);

    if (xf32) {
        proj_kernel<true><<<dim3(512, 16), 256, 0, stream>>>(
            inputs, Wi, Wf, Wo, Wc, bip, bfp, bop, bcp, xproj);
        scan_kernel<true><<<16, 256, 0, stream>>>(
            Wd, bd, Ui, Uf, Uo, Uc, xproj, decay, ring, out);
    } else {
        proj_kernel<false><<<dim3(512, 16), 256, 0, stream>>>(
            inputs, Wi, Wf, Wo, Wc, bip, bfp, bop, bcp, xproj);
        scan_kernel<false><<<16, 256, 0, stream>>>(
            Wd, bd, Ui, Uf, Uo, Uc, xproj, decay, ring, out);
    }
}

// Round 2
// 71958.459 us; speedup vs baseline: 2.8238x; 2.8238x over previous
//
#include <hip/hip_runtime.h>
#include <stdint.h>
#include <stddef.h>

#define TT 32768
#define HH 256

// ---------- bf16 helpers (manual, RNE) ----------
__device__ __forceinline__ float bf2f(unsigned short u) {
    unsigned int x = ((unsigned int)u) << 16;
    float f;
    __builtin_memcpy(&f, &x, 4);
    return f;
}
__device__ __forceinline__ unsigned short f2bf(float f) {
    unsigned int x;
    __builtin_memcpy(&x, &f, 4);
    unsigned int r = x + 0x7fffu + ((x >> 16) & 1u);
    return (unsigned short)(r >> 16);
}

// ---------- init: decay table + exchange-ring reset (runs every launch) ----------
// Ring reset uses agent-scope stores (write-through past L2) so the zeroed tags
// are visible to the scan kernel's L2-bypassing atomic polls.
__global__ void init_kernel(const int* __restrict__ ca,
                            float* __restrict__ decay,
                            unsigned long long* __restrict__ ring) {
    int i = blockIdx.x * 256 + threadIdx.x;
    if (i < TT) {
        float d = (i == 0) ? 0.f : (float)(ca[i] - ca[i - 1]);
        decay[i] = 1.f / logf(2.71828182845904523f + d);
    }
    if (i < 512)
        __hip_atomic_store(&ring[i], 0ull, __ATOMIC_RELAXED, __HIP_MEMORY_SCOPE_AGENT);
}

// ---------- input-side projections: xproj[t][g*256+col] = inputs@W_g + b_g ----------
template <bool XF32>
__global__ __launch_bounds__(256) void proj_kernel(
    const float* __restrict__ A,
    const float* __restrict__ W0, const float* __restrict__ W1,
    const float* __restrict__ W2, const float* __restrict__ W3,
    const float* __restrict__ B0, const float* __restrict__ B1,
    const float* __restrict__ B2, const float* __restrict__ B3,
    void* __restrict__ xproj) {
    __shared__ float As[32][65];
    __shared__ float Bs[32][65];
    const int tid = threadIdx.x;
    const int bm = blockIdx.x;   // 0..511 (t tiles)
    const int by = blockIdx.y;   // 0..15  (gate-col tiles)
    const int g = by >> 2;
    const int col0 = (by & 3) << 6;
    const float* W = (g == 0) ? W0 : (g == 1) ? W1 : (g == 2) ? W2 : W3;
    const float* Bv = (g == 0) ? B0 : (g == 1) ? B1 : (g == 2) ? B2 : B3;
    const int t0 = bm << 6;

    float acc[4][4] = {};
    const int tm = (tid & 15) << 2;
    const int tn = (tid >> 4) << 2;
    const int lrow = tid >> 2;
    const int lk = (tid & 3) << 3;
    const int brow = tid & 63;
    const int bk = (tid >> 6) << 3;

    for (int k0 = 0; k0 < 256; k0 += 32) {
        const float* asrc = A + (size_t)(t0 + lrow) * 256 + k0 + lk;
        float4 a0 = *(const float4*)asrc;
        float4 a1 = *(const float4*)(asrc + 4);
        As[lk + 0][lrow] = a0.x; As[lk + 1][lrow] = a0.y;
        As[lk + 2][lrow] = a0.z; As[lk + 3][lrow] = a0.w;
        As[lk + 4][lrow] = a1.x; As[lk + 5][lrow] = a1.y;
        As[lk + 6][lrow] = a1.z; As[lk + 7][lrow] = a1.w;
#pragma unroll
        for (int j = 0; j < 8; j++)
            Bs[bk + j][brow] = W[(size_t)(k0 + bk + j) * 256 + col0 + brow];
        __syncthreads();
#pragma unroll
        for (int kk = 0; kk < 32; ++kk) {
            float av[4], bv[4];
#pragma unroll
            for (int i = 0; i < 4; i++) av[i] = As[kk][tm + i];
#pragma unroll
            for (int j = 0; j < 4; j++) bv[j] = Bs[kk][tn + j];
#pragma unroll
            for (int i = 0; i < 4; i++)
#pragma unroll
                for (int j = 0; j < 4; j++)
                    acc[i][j] = fmaf(av[i], bv[j], acc[i][j]);
        }
        __syncthreads();
    }
#pragma unroll
    for (int i = 0; i < 4; i++) {
        const size_t rowoff = (size_t)(t0 + tm + i) * 1024 + ((size_t)g << 8) + col0;
#pragma unroll
        for (int j = 0; j < 4; j++) {
            float v = acc[i][j] + Bv[col0 + tn + j];
            if (XF32) ((float*)xproj)[rowoff + tn + j] = v;
            else      ((unsigned short*)xproj)[rowoff + tn + j] = f2bf(v);
        }
    }
}

// ---------- sequential scan: 16 persistent blocks, register-resident weights ----------
// Block b owns output cols [16b, 16b+16). Thread (cl = tid>>4, ks = tid&15):
//   col = 16b+cl, k-slice = [16ks, 16ks+16). Weights w[5][16] in VGPRs.
// Exchange: ring[2][256] u64: low32 = (tag<<16)|h_bf16, high32 = (tag<<16)|c_bf16,
// tag = t+1 after step t. Depth-2 ring race-free by barrier transitivity (a writer
// can only reach step t+2's overwrite of slot p after observing every block's
// step-t+1 tags, which were published after those blocks consumed slot p).
// Consumer protocol (R2): each thread polls exactly ONE word (col = tid), then
// redistributes via a parity-double-buffered, stride-17-swizzled LDS array with a
// single __syncthreads per step. One barrier/step + LDS parity is race-free by the
// same transitivity argument (a thread at step t+2 must have passed step t+1's
// barrier, which every reader of step t's buffer reached only after its reads).
template <bool XF32>
__global__ __launch_bounds__(256, 1) void scan_kernel(
    const float* __restrict__ Wd, const float* __restrict__ bd,
    const float* __restrict__ Ui, const float* __restrict__ Uf,
    const float* __restrict__ Uo, const float* __restrict__ Uc,
    const void* __restrict__ xproj, const float* __restrict__ decay,
    unsigned long long* __restrict__ ring,
    float* __restrict__ out) {
    const int b = blockIdx.x, tid = threadIdx.x;
    const int cl = tid >> 4, ks = tid & 15;
    const int col = (b << 4) + cl;

    // hcm[parity][ (col&15)*17 + (col>>4) ] = (h,c) of col. Reads: hcm[p][j*17+ks]
    // across a wave hit 16 distinct banks x 4-lane broadcast -> conflict-free.
    __shared__ float2 hcm[2][272];

    float w[5][16];
    {
        const float* mats[5] = {Wd, Ui, Uf, Uo, Uc};
#pragma unroll
        for (int m = 0; m < 5; m++)
#pragma unroll
            for (int j = 0; j < 16; j++)
                w[m][j] = mats[m][(size_t)((ks << 4) + j) * 256 + col];
    }
    const float bdv = bd[col];
    const bool owner = (ks == 0);
    const int myslot = (tid & 15) * 17 + (tid >> 4);
    float c_own = 0.f;

    for (int t = 0; t < TT; ++t) {
        // issue independent loads first so they fly under the poll
        float xi = 0.f, xf = 0.f, xo = 0.f, xc = 0.f, dt_ = 0.f;
        if (owner) {
            dt_ = decay[t];
            if (XF32) {
                const float* xp = (const float*)xproj + (size_t)t * 1024;
                xi = xp[col]; xf = xp[col + 256]; xo = xp[col + 512]; xc = xp[col + 768];
            } else {
                const unsigned short* xp = (const unsigned short*)xproj + (size_t)t * 1024;
                xi = bf2f(xp[col]); xf = bf2f(xp[col + 256]);
                xo = bf2f(xp[col + 512]); xc = bf2f(xp[col + 768]);
            }
        }

        float hs[16], cs[16];
        if (t == 0) {
#pragma unroll
            for (int j = 0; j < 16; j++) { hs[j] = 0.f; cs[j] = 0.f; }
        } else {
            const int p = t & 1;
            unsigned long long* ap = ring + (size_t)((t - 1) & 1) * 256 + tid;
            const unsigned int want = (unsigned int)t;  // tag of state after step t-1
            unsigned long long vv;
            do {
                vv = __hip_atomic_load(ap, __ATOMIC_RELAXED, __HIP_MEMORY_SCOPE_AGENT);
            } while ((((unsigned int)vv) >> 16) != want);
            hcm[p][myslot] = make_float2(bf2f((unsigned short)(vv & 0xffffu)),
                                         bf2f((unsigned short)((vv >> 32) & 0xffffu)));
            __syncthreads();
#pragma unroll
            for (int j = 0; j < 16; j++) {
                float2 pc = hcm[p][j * 17 + ks];
                hs[j] = pc.x; cs[j] = pc.y;
            }
        }

        float a0 = 0.f, a1 = 0.f, a2 = 0.f, a3 = 0.f, a4 = 0.f;
#pragma unroll
        for (int j = 0; j < 16; j++) {
            a0 = fmaf(cs[j], w[0][j], a0);
            a1 = fmaf(hs[j], w[1][j], a1);
            a2 = fmaf(hs[j], w[2][j], a2);
            a3 = fmaf(hs[j], w[3][j], a3);
            a4 = fmaf(hs[j], w[4][j], a4);
        }
        // butterfly reduce over the 16-lane k-slice group (lane bits 0..3)
#pragma unroll
        for (int m = 1; m <= 8; m <<= 1) {
            a0 += __shfl_xor(a0, m);
            a1 += __shfl_xor(a1, m);
            a2 += __shfl_xor(a2, m);
            a3 += __shfl_xor(a3, m);
            a4 += __shfl_xor(a4, m);
        }

        if (owner) {
            float s = tanhf(a0 + bdv);
            float adj = (c_own - s) + s * dt_;
            float iv = 1.f / (1.f + __expf(-(a1 + xi)));
            float fv = 1.f / (1.f + __expf(-(a2 + xf)));
            float ov = 1.f / (1.f + __expf(-(a3 + xo)));
            float gv = tanhf(a4 + xc);
            float cn = fv * adj + iv * gv;
            float hn = ov * tanhf(c_own);          // uses PREV memory, per reference
            out[(size_t)t * 256 + col] = hn;
            unsigned int tag = (unsigned int)(t + 1);
            unsigned int w0 = (tag << 16) | (unsigned int)f2bf(hn);
            unsigned int w1 = (tag << 16) | (unsigned int)f2bf(cn);
            unsigned long long pv = (((unsigned long long)w1) << 32) | (unsigned long long)w0;
            __hip_atomic_store(ring + (size_t)(t & 1) * 256 + col, pv,
                               __ATOMIC_RELAXED, __HIP_MEMORY_SCOPE_AGENT);
            c_own = cn;
        }
    }
}

extern "C" void kernel_launch(void* const* d_in, const int* in_sizes, int n_in,
                              void* d_out, int out_size, void* d_ws, size_t ws_size,
                              hipStream_t stream) {
    const float* inputs = (const float*)d_in[0];
    const int* created = (const int*)d_in[1];
    const float* Wd = (const float*)d_in[2];
    // d_in[3] = U_d : unused by the reference
    const float* bd = (const float*)d_in[4];
    const float* Wf = (const float*)d_in[5];
    const float* Uf = (const float*)d_in[6];
    const float* bfp = (const float*)d_in[7];
    const float* Wi = (const float*)d_in[8];
    const float* Ui = (const float*)d_in[9];
    const float* bip = (const float*)d_in[10];
    const float* Wo = (const float*)d_in[11];
    const float* Uo = (const float*)d_in[12];
    const float* bop = (const float*)d_in[13];
    const float* Wc = (const float*)d_in[14];
    const float* Uc = (const float*)d_in[15];
    const float* bcp = (const float*)d_in[16];
    float* out = (float*)d_out;

    char* ws = (char*)d_ws;
    const size_t off_decay = 0;                    // 32768 * 4      = 131072
    const size_t off_ring  = 131072;               // 2*256*8        = 4096
    const size_t off_xproj = 135168;               // 33 * 4096, aligned
    const size_t need_f32 = off_xproj + (size_t)TT * 1024 * 4;  // ~128.1 MiB

    float* decay = (float*)(ws + off_decay);
    unsigned long long* ring = (unsigned long long*)(ws + off_ring);
    void* xproj = (void*)(ws + off_xproj);
    const bool xf32 = (ws_size >= need_f32);

    init_kernel<<<128, 256, 0, stream>>>(created, decay, ring);

    if (xf32) {
        proj_kernel<true><<<dim3(512, 16), 256, 0, stream>>>(
            inputs, Wi, Wf, Wo, Wc, bip, bfp, bop, bcp, xproj);
        scan_kernel<true><<<16, 256, 0, stream>>>(
            Wd, bd, Ui, Uf, Uo, Uc, xproj, decay, ring, out);
    } else {
        proj_kernel<false><<<dim3(512, 16), 256, 0, stream>>>(
            inputs, Wi, Wf, Wo, Wc, bip, bfp, bop, bcp, xproj);
        scan_kernel<false><<<16, 256, 0, stream>>>(
            Wd, bd, Ui, Uf, Uo, Uc, xproj, decay, ring, out);
    }
}